// Round 1
// baseline (4355.894 us; speedup 1.0000x reference)
//
#include <hip/hip_runtime.h>

// JAX threefry_partitionable semantics (default since jax 0.4.36).
// If validation fails with O(100) absmax, flip to 0 (legacy pairing).
#define PARTITIONABLE 1

#define B_SZ 32
#define T_STEPS 64
#define N_IN 64
#define N_HID 512
#define N_OUT 16
#define NOISE_START_T 16

#define WGS 256
#define WGS_PER_B 16
#define ROWS_PER_WG 32
#define NWG (B_SZ * WGS_PER_B)  // 512

// d_out float offsets
#define HL_OFF  0
#define OL_OFF  (B_SZ * T_STEPS * N_HID)          // 1048576
#define HID_OFF (OL_OFF + B_SZ * T_STEPS * N_OUT) // 1081344
#define NJ_OFF  (HID_OFF + B_SZ * N_HID)          // 1097728

// ws layout: [0,4096) bytes = barrier counters; floats after.
#define CNT_BYTES 4096
#define XWB_OFF 0                                  // [32][64][512]
#define DJP_OFF (B_SZ * T_STEPS * N_HID)           // [2 par][2 kind][32 b][16 blk][512]

__device__ __forceinline__ void tf2x32(unsigned k0, unsigned k1, unsigned x0, unsigned x1,
                                       unsigned& o0, unsigned& o1) {
  unsigned ks2 = k0 ^ k1 ^ 0x1BD11BDAu;
#define TFR(r) { x0 += x1; x1 = (x1 << (r)) | (x1 >> (32 - (r))); x1 ^= x0; }
  x0 += k0; x1 += k1;
  TFR(13) TFR(15) TFR(26) TFR(6)
  x0 += k1; x1 += ks2 + 1u;
  TFR(17) TFR(29) TFR(16) TFR(24)
  x0 += ks2; x1 += k0 + 2u;
  TFR(13) TFR(15) TFR(26) TFR(6)
  x0 += k0; x1 += k1 + 3u;
  TFR(17) TFR(29) TFR(16) TFR(24)
  x0 += k1; x1 += ks2 + 4u;
  TFR(13) TFR(15) TFR(26) TFR(6)
  x0 += ks2; x1 += k0 + 5u;
#undef TFR
  o0 = x0; o1 = x1;
}

#if PARTITIONABLE
__device__ __forceinline__ unsigned rbits(unsigned kx, unsigned ky, unsigned n, unsigned /*half*/) {
  unsigned a, b; tf2x32(kx, ky, 0u, n, a, b); return a ^ b;
}
__device__ __forceinline__ void make_keys(int t, unsigned& k1x, unsigned& k1y,
                                          unsigned& k2x, unsigned& k2y) {
  unsigned f0, f1; tf2x32(0u, 1234u, 0u, (unsigned)t, f0, f1);
  tf2x32(f0, f1, 0u, 0u, k1x, k1y);
  tf2x32(f0, f1, 0u, 1u, k2x, k2y);
}
#else
__device__ __forceinline__ unsigned rbits(unsigned kx, unsigned ky, unsigned n, unsigned half) {
  unsigned lo = (n < half) ? n : (n - half);
  unsigned a, b; tf2x32(kx, ky, lo, lo + half, a, b);
  return (n < half) ? a : b;
}
__device__ __forceinline__ void make_keys(int t, unsigned& k1x, unsigned& k1y,
                                          unsigned& k2x, unsigned& k2y) {
  unsigned f0, f1; tf2x32(0u, 1234u, 0u, (unsigned)t, f0, f1);
  unsigned a0, a1, b0, b1;
  tf2x32(f0, f1, 0u, 2u, a0, a1);
  tf2x32(f0, f1, 1u, 3u, b0, b1);
  k1x = a0; k1y = b0; k2x = a1; k2y = b1;
}
#endif

// XLA-exact: uniform(lo=nextafter(-1,0), hi=1) then sqrt(2)*erfinv (Giles poly, log1p form)
__device__ __forceinline__ float nrm_from_bits(unsigned bits) {
  const float lo = -0.99999994039535522461f;
  float f = __uint_as_float((bits >> 9) | 0x3F800000u) - 1.0f;
  float u = fmaxf(lo, f * 2.0f + lo);
  float w = -log1pf(-u * u);
  float p;
  if (w < 5.0f) {
    w -= 2.5f;
    p =            2.81022636e-08f;
    p = fmaf(p, w, 3.43273939e-07f);
    p = fmaf(p, w, -3.5233877e-06f);
    p = fmaf(p, w, -4.39150654e-06f);
    p = fmaf(p, w, 0.00021858087f);
    p = fmaf(p, w, -0.00125372503f);
    p = fmaf(p, w, -0.00417768164f);
    p = fmaf(p, w, 0.246640727f);
    p = fmaf(p, w, 1.50140941f);
  } else {
    w = sqrtf(w) - 3.0f;
    p =            -0.000200214257f;
    p = fmaf(p, w, 0.000100950558f);
    p = fmaf(p, w, 0.00134934322f);
    p = fmaf(p, w, -0.00367342844f);
    p = fmaf(p, w, 0.00573950773f);
    p = fmaf(p, w, -0.0076224613f);
    p = fmaf(p, w, 0.00943887047f);
    p = fmaf(p, w, 1.00167406f);
    p = fmaf(p, w, 2.83297682f);
  }
  return 1.41421356f * (p * u);
}

__global__ __launch_bounds__(WGS, 2) void rnn_fused(
    const float* __restrict__ x, const float* __restrict__ h0_in,
    const float* __restrict__ w_in, const float* __restrict__ w_hh,
    const float* __restrict__ b_hh, const float* __restrict__ w_out,
    const float* __restrict__ alpha, const float* __restrict__ beta,
    float* __restrict__ out, float* __restrict__ wsf, unsigned* __restrict__ cnts) {
  extern __shared__ float smem[];
  float* wh_lds  = smem;               // [32][513] padded transpose slice
  float* h_lds   = smem + 32 * 513;    // [512]
  float* a_lds   = h_lds + N_HID;      // [512]
  float* red_lds = a_lds + N_HID;      // [256]

  const int tid = threadIdx.x;
  const int b   = blockIdx.x >> 4;
  const int blk = blockIdx.x & 15;
  const int i0  = blk * ROWS_PER_WG;
  const int j0 = tid, j1 = tid + WGS;

  float* diff = out + NJ_OFF + (size_t)b * (N_HID * N_HID);
  float* hl = out + HL_OFF;
  float* ol = out + OL_OFF;
  float* hid = out + HID_OFF;
  float* xwb = wsf + XWB_OFF;
  unsigned* cnt = cnts + (size_t)b * 32;  // 128B-spaced per-batch barrier counter

  // ---- prologue (all per-WG local; xwb is group-shared, covered by barrier 0) ----
  for (int idx = tid; idx < ROWS_PER_WG * N_HID; idx += WGS) {
    int j = idx >> 5, ii = idx & 31;
    wh_lds[ii * 513 + j] = w_hh[j * N_HID + (i0 + ii)];  // w_hh^T slice
  }
  for (int j = tid; j < N_HID; j += WGS) {
    float h = h0_in[b * N_HID + j];
    h_lds[j] = h;
    a_lds[j] = tanhf(h);
  }
  for (int idx = tid; idx < ROWS_PER_WG * N_HID; idx += WGS) {
    int ii = idx >> 9, j = idx & 511;
    diff[(size_t)(i0 + ii) * N_HID + j] = 0.f;  // diff = new_j - w_hh starts at 0
  }
  // xwb[b][t][j] = x_t @ w_in^T ; this WG covers t in [blk*4, blk*4+4)
  for (int e = 0; e < 8; ++e) {
    int idx = tid + WGS * e;
    int tt = (idx >> 9) + blk * 4;
    int j = idx & 511;
    const float* xr = x + ((size_t)b * T_STEPS + tt) * N_IN;
    const float* wr = w_in + (size_t)j * N_IN;
    float s = 0.f;
#pragma unroll
    for (int k = 0; k < N_IN; ++k) s = fmaf(xr[k], wr[k], s);
    xwb[((size_t)b * T_STEPS + tt) * N_HID + j] = s;
  }
  const float bet0 = beta[j0], bet1 = beta[j1];
  const float sb0 = sqrtf(bet0), sb1 = sqrtf(bet1);
  const float al0 = alpha[j0], al1 = alpha[j1];
  const float sqa0 = sqrtf(al0), sqa1 = sqrtf(al1);
  const float bh0 = b_hh[j0], bh1 = b_hh[j1];
  __syncthreads();

  unsigned barTarget = 0;

  for (int t = 0; t < T_STEPS; ++t) {
    unsigned k1x, k1y, k2x, k2y;
    make_keys(t, k1x, k1y, k2x, k2y);
    const int par = t & 1;

    // ---- phase B: sweep own 32 rows of diff: accumulate a·diff and a·w_hh^T,
    //      apply anti-Hebbian + synaptic-noise update in the same pass ----
    const float aj0 = a_lds[j0], aj1 = a_lds[j1];
    float acc_d0 = 0.f, acc_d1 = 0.f, acc_w0 = 0.f, acc_w1 = 0.f;
#pragma unroll 2
    for (int ii = 0; ii < ROWS_PER_WG; ++ii) {
      const int i = i0 + ii;
      const float ai = a_lds[i];
      float* drow = diff + (size_t)i * N_HID;
      float d0 = drow[j0], d1 = drow[j1];
      float wh0 = wh_lds[ii * 513 + j0], wh1 = wh_lds[ii * 513 + j1];
      acc_d0 = fmaf(ai, d0, acc_d0);
      acc_w0 = fmaf(ai, wh0, acc_w0);
      acc_d1 = fmaf(ai, d1, acc_d1);
      acc_w1 = fmaf(ai, wh1, acc_w1);
      unsigned n0 = (unsigned)(((b * N_HID) + i) * N_HID + j0);
      float z0 = nrm_from_bits(rbits(k2x, k2y, n0, 4194304u));
      float z1 = nrm_from_bits(rbits(k2x, k2y, n0 + 256u, 4194304u));
      drow[j0] = d0 + bet0 * ((z0 * 0.002f) * sb0 - ai * aj0);
      drow[j1] = d1 + bet1 * ((z1 * 0.002f) * sb1 - ai * aj1);
    }
    {
      float* djp_d = wsf + DJP_OFF + (size_t)(((par * 2 + 0) * B_SZ + b) * WGS_PER_B + blk) * N_HID;
      float* djp_w = wsf + DJP_OFF + (size_t)(((par * 2 + 1) * B_SZ + b) * WGS_PER_B + blk) * N_HID;
      djp_d[j0] = acc_d0; djp_d[j1] = acc_d1;
      djp_w[j0] = acc_w0; djp_w[j1] = acc_w1;
    }

    // ---- per-batch barrier (16 WGs), release/acquire, agent scope ----
    barTarget += WGS_PER_B;
    __syncthreads();
    if (tid == 0) {
      __hip_atomic_fetch_add(cnt, 1u, __ATOMIC_RELEASE, __HIP_MEMORY_SCOPE_AGENT);
      while (__hip_atomic_load(cnt, __ATOMIC_RELAXED, __HIP_MEMORY_SCOPE_AGENT) < barTarget)
        __builtin_amdgcn_s_sleep(1);
      (void)__hip_atomic_load(cnt, __ATOMIC_ACQUIRE, __HIP_MEMORY_SCOPE_AGENT);
    }
    __syncthreads();

    // ---- phase C: h update, computed redundantly (bit-identical) in all 16 WGs ----
    {
      const float* dpd = wsf + DJP_OFF + (size_t)((par * 2 + 0) * B_SZ + b) * WGS_PER_B * N_HID;
      const float* dpw = wsf + DJP_OFF + (size_t)((par * 2 + 1) * B_SZ + b) * WGS_PER_B * N_HID;
      float sd0 = 0.f, sd1 = 0.f, sw0 = 0.f, sw1 = 0.f;
#pragma unroll
      for (int k = 0; k < WGS_PER_B; ++k) {
        sd0 += dpd[k * N_HID + j0];
        sd1 += dpd[k * N_HID + j1];
        sw0 += dpw[k * N_HID + j0];
        sw1 += dpw[k * N_HID + j1];
      }
      const float* xwrow = xwb + ((size_t)b * T_STEPS + t) * N_HID;
      float tmp0 = ((xwrow[j0] + sw0) + bh0) + sd0;
      float tmp1 = ((xwrow[j1] + sw1) + bh1) + sd1;
      float hn0 = (1.f - al0) * h_lds[j0] + al0 * tmp0;
      float hn1 = (1.f - al1) * h_lds[j1] + al1 * tmp1;
      if (t >= NOISE_START_T) {
        unsigned m0 = (unsigned)(b * N_HID + j0);
        hn0 += (nrm_from_bits(rbits(k1x, k1y, m0, 8192u)) * 0.05f) * sqa0;
        hn1 += (nrm_from_bits(rbits(k1x, k1y, m0 + 256u, 8192u)) * 0.05f) * sqa1;
      }
      h_lds[j0] = hn0; h_lds[j1] = hn1;
      a_lds[j0] = tanhf(hn0); a_lds[j1] = tanhf(hn1);
      if (blk == 0) {
        float* hlrow = hl + ((size_t)b * T_STEPS + t) * N_HID;
        hlrow[j0] = hn0; hlrow[j1] = hn1;
        if (t == T_STEPS - 1) { hid[b * N_HID + j0] = hn0; hid[b * N_HID + j1] = hn1; }
      }
    }
    __syncthreads();
    if (blk == 0) {  // out = h_new @ w_out^T (tiny, WG-local reduce)
      const int o = tid & 15, q = tid >> 4;
      const float* wo = w_out + o * N_HID;
      float p = 0.f;
#pragma unroll
      for (int m = 0; m < 32; ++m) { int j = q * 32 + m; p = fmaf(h_lds[j], wo[j], p); }
      red_lds[tid] = p;
      __syncthreads();
      if (tid < 16) {
        float s = 0.f;
#pragma unroll
        for (int m = 0; m < 16; ++m) s += red_lds[m * 16 + tid];
        ol[((size_t)b * T_STEPS + t) * N_OUT + tid] = s;
      }
    }
  }

  // ---- epilogue: new_j = diff + w_hh (in place, own rows) ----
  for (int idx = tid; idx < ROWS_PER_WG * N_HID; idx += WGS) {
    int ii = idx >> 9, j = idx & 511;
    size_t o = (size_t)(i0 + ii) * N_HID + j;
    diff[o] = diff[o] + w_hh[(size_t)(i0 + ii) * N_HID + j];
  }
}

extern "C" void kernel_launch(void* const* d_in, const int* in_sizes, int n_in,
                              void* d_out, int out_size, void* d_ws, size_t ws_size,
                              hipStream_t stream) {
  const float* x     = (const float*)d_in[0];
  const float* h0    = (const float*)d_in[1];
  const float* win   = (const float*)d_in[2];
  const float* whh   = (const float*)d_in[3];
  const float* bhh   = (const float*)d_in[4];
  const float* wout  = (const float*)d_in[5];
  const float* alpha = (const float*)d_in[6];
  const float* beta  = (const float*)d_in[7];
  (void)in_sizes; (void)n_in; (void)out_size; (void)ws_size;

  hipMemsetAsync(d_ws, 0, CNT_BYTES, stream);  // zero barrier counters (ws is poisoned)
  float* wsf = (float*)((char*)d_ws + CNT_BYTES);
  unsigned* cnts = (unsigned*)d_ws;
  size_t smem = (size_t)(32 * 513 + N_HID + N_HID + 256) * sizeof(float);  // 70784 B
  rnn_fused<<<NWG, WGS, smem, stream>>>(x, h0, win, whh, bhh, wout, alpha, beta,
                                        (float*)d_out, wsf, cnts);
}

// Round 2
// 4315.969 us; speedup vs baseline: 1.0093x; 1.0093x over previous
//
#include <hip/hip_runtime.h>

#define B_SZ 32
#define T_STEPS 64
#define N_IN 64
#define N_HID 512
#define N_OUT 16
#define NOISE_START_T 16

#define WGS 256
#define WPB 32          // workgroups per batch
#define JPW 16          // j columns per WG
#define IPT 32          // i elements per thread
#define NWG (B_SZ * WPB)  // 1024

// d_out float offsets (hidden_list, output_list, hidden, new_j)
#define HL_OFF  0
#define OL_OFF  (B_SZ * T_STEPS * N_HID)
#define HID_OFF (OL_OFF + B_SZ * T_STEPS * N_OUT)
#define NJ_OFF  (HID_OFF + B_SZ * N_HID)

#define CNT_BYTES 4096

__device__ __forceinline__ void tf2x32(unsigned k0, unsigned k1, unsigned x0, unsigned x1,
                                       unsigned& o0, unsigned& o1) {
  unsigned ks2 = k0 ^ k1 ^ 0x1BD11BDAu;
#define TFR(r) { x0 += x1; x1 = (x1 << (r)) | (x1 >> (32 - (r))); x1 ^= x0; }
  x0 += k0; x1 += k1;
  TFR(13) TFR(15) TFR(26) TFR(6)
  x0 += k1; x1 += ks2 + 1u;
  TFR(17) TFR(29) TFR(16) TFR(24)
  x0 += ks2; x1 += k0 + 2u;
  TFR(13) TFR(15) TFR(26) TFR(6)
  x0 += k0; x1 += k1 + 3u;
  TFR(17) TFR(29) TFR(16) TFR(24)
  x0 += k1; x1 += ks2 + 4u;
  TFR(13) TFR(15) TFR(26) TFR(6)
  x0 += ks2; x1 += k0 + 5u;
#undef TFR
  o0 = x0; o1 = x1;
}

// JAX threefry_partitionable: out[n] = o0^o1 of tf(key, (0, n))  [verified r1]
__device__ __forceinline__ unsigned rbits(unsigned kx, unsigned ky, unsigned n) {
  unsigned a, b; tf2x32(kx, ky, 0u, n, a, b); return a ^ b;
}

// XLA-exact uniform->normal, with fast-log substitution:
// w = -log1p(-u^2) == -log((1-u)(1+u)) ; factored form avoids cancellation.
__device__ __forceinline__ float nrm_from_bits(unsigned bits) {
  const float lo = -0.99999994039535522461f;
  float f = __uint_as_float((bits >> 9) | 0x3F800000u) - 1.0f;
  float u = fmaxf(lo, f * 2.0f + lo);
  float w = -__logf((1.0f - u) * (1.0f + u));
  float p;
  if (w < 5.0f) {
    w -= 2.5f;
    p =            2.81022636e-08f;
    p = fmaf(p, w, 3.43273939e-07f);
    p = fmaf(p, w, -3.5233877e-06f);
    p = fmaf(p, w, -4.39150654e-06f);
    p = fmaf(p, w, 0.00021858087f);
    p = fmaf(p, w, -0.00125372503f);
    p = fmaf(p, w, -0.00417768164f);
    p = fmaf(p, w, 0.246640727f);
    p = fmaf(p, w, 1.50140941f);
  } else {
    w = sqrtf(w) - 3.0f;
    p =            -0.000200214257f;
    p = fmaf(p, w, 0.000100950558f);
    p = fmaf(p, w, 0.00134934322f);
    p = fmaf(p, w, -0.00367342844f);
    p = fmaf(p, w, 0.00573950773f);
    p = fmaf(p, w, -0.0076224613f);
    p = fmaf(p, w, 0.00943887047f);
    p = fmaf(p, w, 1.00167406f);
    p = fmaf(p, w, 2.83297682f);
  }
  return 1.41421356f * (p * u);
}

__global__ __launch_bounds__(WGS, 4) void rnn_fused(
    const float* __restrict__ x, const float* __restrict__ h0_in,
    const float* __restrict__ w_in, const float* __restrict__ w_hh,
    const float* __restrict__ b_hh, const float* __restrict__ w_out,
    const float* __restrict__ alpha, const float* __restrict__ beta,
    float* __restrict__ out, float* __restrict__ aex, unsigned* __restrict__ cnts) {
  __shared__ __align__(16) float buf[JPW][N_HID];   // 32 KB, epilogue transpose
  __shared__ __align__(16) float a_lds[N_HID];      // 2 KB
  __shared__ float red[JPW][2];
  __shared__ float olred[WGS];
  __shared__ unsigned key_lds[T_STEPS][4];          // 1 KB

  const int tid = threadIdx.x;
  const int b   = blockIdx.x >> 5;
  const int blk = blockIdx.x & 31;
  const int jl  = tid >> 4;            // 0..15: owned column (sweep)
  const int ib  = tid & 15;            // i-block
  const int i0  = ib * IPT;
  const int jg  = blk * JPW + jl;      // global column for sweep
  const int jc  = blk * JPW + (tid & 15); // column for phase C (tid<16)

  float* hl  = out + HL_OFF;
  float* ol  = out + OL_OFF;
  float* hid = out + HID_OFF;
  float* nj  = out + NJ_OFF + (size_t)b * (N_HID * N_HID);
  unsigned* cnt = cnts + (size_t)b * 32;
  const float* whrow = w_hh + (size_t)jg * N_HID;

  // ---- prologue ----
  // keys for all timesteps, once (t = tid)
  if (tid < T_STEPS) {
    unsigned f0, f1, a0, a1, b0, b1;
    tf2x32(0u, 1234u, 0u, (unsigned)tid, f0, f1);
    tf2x32(f0, f1, 0u, 0u, a0, a1);   // k1 (neuron noise)
    tf2x32(f0, f1, 0u, 1u, b0, b1);   // k2 (synaptic noise)
    key_lds[tid][0] = a0; key_lds[tid][1] = a1;
    key_lds[tid][2] = b0; key_lds[tid][3] = b1;
  }
  // per-thread constants
  const float bet = beta[jg];
  const float sb  = sqrtf(bet);
  const float alc = alpha[jc];
  const float sqac = sqrtf(alc);
  const float bhc = b_hh[jc];
  float h_reg = h0_in[b * N_HID + jc];  // used by tid<16
  // a(0) = tanh(h0), computed locally (redundant per WG)
  a_lds[tid]       = tanhf(h0_in[b * N_HID + tid]);
  a_lds[tid + 256] = tanhf(h0_in[b * N_HID + tid + 256]);

  // plastic deviation diff[jg][i0..i0+31] lives in registers, starts at 0
  float4 d[8];
#pragma unroll
  for (int k = 0; k < 8; ++k) d[k] = make_float4(0.f, 0.f, 0.f, 0.f);

  __syncthreads();

  unsigned target = 0;
  const unsigned nb = (unsigned)(b * N_HID * N_HID) + (unsigned)jg;

  for (int t = 0; t < T_STEPS; ++t) {
    unsigned k1x = __builtin_amdgcn_readfirstlane(key_lds[t][0]);
    unsigned k1y = __builtin_amdgcn_readfirstlane(key_lds[t][1]);
    unsigned k2x = __builtin_amdgcn_readfirstlane(key_lds[t][2]);
    unsigned k2y = __builtin_amdgcn_readfirstlane(key_lds[t][3]);

    // ---- sweep own 32 elements: accumulate a.diff and a.w_hh^T, update diff ----
    const float ajg = a_lds[jg];
    float accd = 0.f, accw = 0.f;
#pragma unroll
    for (int k = 0; k < 8; ++k) {
      const int i = i0 + k * 4;
      float4 av = *(const float4*)&a_lds[i];
      float4 wv = *(const float4*)&whrow[i];
      accw = fmaf(av.x, wv.x, accw); accw = fmaf(av.y, wv.y, accw);
      accw = fmaf(av.z, wv.z, accw); accw = fmaf(av.w, wv.w, accw);
      accd = fmaf(av.x, d[k].x, accd); accd = fmaf(av.y, d[k].y, accd);
      accd = fmaf(av.z, d[k].z, accd); accd = fmaf(av.w, d[k].w, accd);
      const unsigned n = nb + (unsigned)i * 512u;
      float z0 = nrm_from_bits(rbits(k2x, k2y, n));
      float z1 = nrm_from_bits(rbits(k2x, k2y, n + 512u));
      float z2 = nrm_from_bits(rbits(k2x, k2y, n + 1024u));
      float z3 = nrm_from_bits(rbits(k2x, k2y, n + 1536u));
      d[k].x = d[k].x + bet * ((z0 * 0.002f) * sb - av.x * ajg);
      d[k].y = d[k].y + bet * ((z1 * 0.002f) * sb - av.y * ajg);
      d[k].z = d[k].z + bet * ((z2 * 0.002f) * sb - av.z * ajg);
      d[k].w = d[k].w + bet * ((z3 * 0.002f) * sb - av.w * ajg);
    }
    // 16-lane butterfly reduce (lanes sharing jl)
#pragma unroll
    for (int m = 1; m < 16; m <<= 1) {
      accd += __shfl_xor(accd, m);
      accw += __shfl_xor(accw, m);
    }
    if (ib == 0) { red[jl][0] = accd; red[jl][1] = accw; }
    __syncthreads();

    // ---- phase C: h update for own 16 columns (tid<16), non-redundant ----
    if (tid < JPW) {
      const float sd = red[tid][0], sw = red[tid][1];
      const float* xr = x + ((size_t)b * T_STEPS + t) * N_IN;
      const float* wr = w_in + (size_t)jc * N_IN;
      float xw = 0.f;
#pragma unroll
      for (int k = 0; k < N_IN; ++k) xw = fmaf(xr[k], wr[k], xw);
      float tmp = ((xw + sw) + bhc) + sd;
      float hn = (1.f - alc) * h_reg + alc * tmp;
      if (t >= NOISE_START_T) {
        unsigned m0 = (unsigned)(b * N_HID + jc);
        hn += (nrm_from_bits(rbits(k1x, k1y, m0)) * 0.05f) * sqac;
      }
      h_reg = hn;
      float an = tanhf(hn);
      aex[(((t + 1) & 1) * B_SZ + b) * N_HID + jc] = an;
      hl[((size_t)b * T_STEPS + t) * N_HID + jc] = hn;
      if (t == T_STEPS - 1) hid[b * N_HID + jc] = hn;
    }
    __syncthreads();

    // ---- per-batch barrier (32 WGs) ----
    target += WPB;
    if (tid == 0) {
      __hip_atomic_fetch_add(cnt, 1u, __ATOMIC_RELEASE, __HIP_MEMORY_SCOPE_AGENT);
      while (__hip_atomic_load(cnt, __ATOMIC_RELAXED, __HIP_MEMORY_SCOPE_AGENT) < target)
        __builtin_amdgcn_s_sleep(2);
      (void)__hip_atomic_load(cnt, __ATOMIC_ACQUIRE, __HIP_MEMORY_SCOPE_AGENT);
    }
    __syncthreads();

    // ---- refill a_lds from exchange; blk0 computes out-projection partials ----
    {
      const int pr = (t + 1) & 1;
      a_lds[tid]       = aex[(pr * B_SZ + b) * N_HID + tid];
      a_lds[tid + 256] = aex[(pr * B_SZ + b) * N_HID + tid + 256];
    }
    if (blk == 0) {
      const float* hrow = hl + ((size_t)b * T_STEPS + t) * N_HID;
      const int o = tid & 15, q = tid >> 4;
      const float* wo = w_out + o * N_HID;
      float p = 0.f;
#pragma unroll
      for (int m = 0; m < 32; ++m) { int j = q * 32 + m; p = fmaf(hrow[j], wo[j], p); }
      olred[tid] = p;
    }
    __syncthreads();
    if (blk == 0 && tid < N_OUT) {
      float s = 0.f;
#pragma unroll
      for (int m = 0; m < 16; ++m) s += olred[m * 16 + tid];
      ol[((size_t)b * T_STEPS + t) * N_OUT + tid] = s;
    }
  }

  // ---- epilogue: registers -> LDS -> transposed coalesced write of new_j ----
#pragma unroll
  for (int k = 0; k < 8; ++k) *(float4*)&buf[jl][i0 + k * 4] = d[k];
  __syncthreads();
#pragma unroll
  for (int c = 0; c < 2; ++c) {
    const int i = c * 256 + tid;
    const float* whr = w_hh + (size_t)i * N_HID + blk * JPW;
    float* orow = nj + (size_t)i * N_HID + blk * JPW;
#pragma unroll
    for (int jj = 0; jj < JPW; ++jj) orow[jj] = buf[jj][i] + whr[jj];
  }
}

extern "C" void kernel_launch(void* const* d_in, const int* in_sizes, int n_in,
                              void* d_out, int out_size, void* d_ws, size_t ws_size,
                              hipStream_t stream) {
  const float* x     = (const float*)d_in[0];
  const float* h0    = (const float*)d_in[1];
  const float* win   = (const float*)d_in[2];
  const float* whh   = (const float*)d_in[3];
  const float* bhh   = (const float*)d_in[4];
  const float* wout  = (const float*)d_in[5];
  const float* alpha = (const float*)d_in[6];
  const float* beta  = (const float*)d_in[7];
  (void)in_sizes; (void)n_in; (void)out_size; (void)ws_size;

  hipMemsetAsync(d_ws, 0, CNT_BYTES, stream);  // zero per-batch barrier counters
  unsigned* cnts = (unsigned*)d_ws;
  float* aex = (float*)((char*)d_ws + CNT_BYTES);  // [2][B_SZ][N_HID]
  rnn_fused<<<NWG, WGS, 0, stream>>>(x, h0, win, whh, bhh, wout, alpha, beta,
                                     (float*)d_out, aex, cnts);
}

// Round 3
// 2276.081 us; speedup vs baseline: 1.9138x; 1.8962x over previous
//
#include <hip/hip_runtime.h>

#define B_SZ 32
#define T_STEPS 64
#define N_IN 64
#define N_HID 512
#define N_OUT 16
#define NOISE_START_T 16

#define WGS 256
#define WPB 32          // workgroups per batch
#define JPW 16          // j columns per WG
#define NWG (B_SZ * WPB)  // 1024

// d_out float offsets (hidden_list, output_list, hidden, new_j)
#define HL_OFF  0
#define OL_OFF  (B_SZ * T_STEPS * N_HID)
#define HID_OFF (OL_OFF + B_SZ * T_STEPS * N_OUT)
#define NJ_OFF  (HID_OFF + B_SZ * N_HID)

#define CNT_BYTES 4096

__device__ __forceinline__ void tf2x32(unsigned k0, unsigned k1, unsigned x0, unsigned x1,
                                       unsigned& o0, unsigned& o1) {
  unsigned ks2 = k0 ^ k1 ^ 0x1BD11BDAu;
#define TFR(r) { x0 += x1; x1 = (x1 << (r)) | (x1 >> (32 - (r))); x1 ^= x0; }
  x0 += k0; x1 += k1;
  TFR(13) TFR(15) TFR(26) TFR(6)
  x0 += k1; x1 += ks2 + 1u;
  TFR(17) TFR(29) TFR(16) TFR(24)
  x0 += ks2; x1 += k0 + 2u;
  TFR(13) TFR(15) TFR(26) TFR(6)
  x0 += k0; x1 += k1 + 3u;
  TFR(17) TFR(29) TFR(16) TFR(24)
  x0 += k1; x1 += ks2 + 4u;
  TFR(13) TFR(15) TFR(26) TFR(6)
  x0 += ks2; x1 += k0 + 5u;
#undef TFR
  o0 = x0; o1 = x1;
}

// JAX threefry_partitionable: out[n] = o0^o1 of tf(key, (0, n))  [verified r1]
__device__ __forceinline__ unsigned rbits(unsigned kx, unsigned ky, unsigned n) {
  unsigned a, b; tf2x32(kx, ky, 0u, n, a, b); return a ^ b;
}

// XLA-exact uniform->normal with factored fast-log (validated r2, absmax 4.0)
__device__ __forceinline__ float nrm_from_bits(unsigned bits) {
  const float lo = -0.99999994039535522461f;
  float f = __uint_as_float((bits >> 9) | 0x3F800000u) - 1.0f;
  float u = fmaxf(lo, f * 2.0f + lo);
  float w = -__logf((1.0f - u) * (1.0f + u));
  float p;
  if (w < 5.0f) {
    w -= 2.5f;
    p =            2.81022636e-08f;
    p = fmaf(p, w, 3.43273939e-07f);
    p = fmaf(p, w, -3.5233877e-06f);
    p = fmaf(p, w, -4.39150654e-06f);
    p = fmaf(p, w, 0.00021858087f);
    p = fmaf(p, w, -0.00125372503f);
    p = fmaf(p, w, -0.00417768164f);
    p = fmaf(p, w, 0.246640727f);
    p = fmaf(p, w, 1.50140941f);
  } else {
    w = sqrtf(w) - 3.0f;
    p =            -0.000200214257f;
    p = fmaf(p, w, 0.000100950558f);
    p = fmaf(p, w, 0.00134934322f);
    p = fmaf(p, w, -0.00367342844f);
    p = fmaf(p, w, 0.00573950773f);
    p = fmaf(p, w, -0.0076224613f);
    p = fmaf(p, w, 0.00943887047f);
    p = fmaf(p, w, 1.00167406f);
    p = fmaf(p, w, 2.83297682f);
  }
  return 1.41421356f * (p * u);
}

// relaxed agent-scope atomics: coherent at MALL (sc1), NO L2 flush/inv.
__device__ __forceinline__ void pubf(float* p, float v) {
  __hip_atomic_store(p, v, __ATOMIC_RELAXED, __HIP_MEMORY_SCOPE_AGENT);
}
__device__ __forceinline__ float rdf(float* p) {
  return __hip_atomic_load(p, __ATOMIC_RELAXED, __HIP_MEMORY_SCOPE_AGENT);
}

__global__ __launch_bounds__(WGS, 4) void rnn_fused(
    const float* __restrict__ x, const float* __restrict__ h0_in,
    const float* __restrict__ w_in, const float* __restrict__ w_hh,
    const float* __restrict__ b_hh, const float* __restrict__ w_out,
    const float* __restrict__ alpha, const float* __restrict__ beta,
    float* __restrict__ out, float* __restrict__ wsf, unsigned* __restrict__ cnts) {
  // 32 KB LDS union -> 4 WGs/CU guaranteed (barrier co-residency requirement)
  __shared__ __align__(16) unsigned char smem[32768];
  float* buf      = (float*)smem;               // [16][512] epilogue only
  float* a_lds    = (float*)smem;               // [512]
  float* h_lds    = (float*)(smem + 2048);      // [512] (blk0 ol)
  float* xw_lds   = (float*)(smem + 4096);      // [64][16]
  unsigned* keyl  = (unsigned*)(smem + 8192);   // [64][4]
  float* olred    = (float*)(smem + 9216);      // [256]

  const int tid = threadIdx.x;
  const int b   = blockIdx.x >> 5;
  const int blk = blockIdx.x & 31;
  const int jl  = tid >> 4;
  const int ib  = tid & 15;
  const int i0  = ib * 32;
  const int jg  = blk * JPW + jl;
  const bool leader = (ib == 0);

  float* hl  = out + HL_OFF;
  float* ol  = out + OL_OFF;
  float* hid = out + HID_OFF;
  float* nj  = out + NJ_OFF + (size_t)b * (N_HID * N_HID);
  unsigned* cnt = cnts + (size_t)b * 32;
  float* hex  = wsf;                      // [2][B][512] published h
  float* aexb = wsf + 2 * B_SZ * N_HID;   // [2][B][512] published a=tanh(h)

  // ---- prologue ----
  if (tid < T_STEPS) {
    unsigned f0, f1, a0, a1, b0, b1;
    tf2x32(0u, 1234u, 0u, (unsigned)tid, f0, f1);
    tf2x32(f0, f1, 0u, 0u, a0, a1);
    tf2x32(f0, f1, 0u, 1u, b0, b1);
    keyl[tid * 4 + 0] = a0; keyl[tid * 4 + 1] = a1;
    keyl[tid * 4 + 2] = b0; keyl[tid * 4 + 3] = b1;
  }
  // xw_lds[t][jj] = x[b,t,:] . w_in[blk*16+jj,:]  (same fmaf chain as r2 phase C)
#pragma unroll
  for (int r = 0; r < 4; ++r) {
    int m = r * 256 + tid;
    int tt = m >> 4, jj = m & 15;
    const float* xr = x + ((size_t)b * T_STEPS + tt) * N_IN;
    const float* wr = w_in + (size_t)(blk * JPW + jj) * N_IN;
    float s = 0.f;
#pragma unroll
    for (int k = 0; k < N_IN; ++k) s = fmaf(xr[k], wr[k], s);
    xw_lds[tt * JPW + jj] = s;
  }
  a_lds[tid]       = tanhf(h0_in[b * N_HID + tid]);
  a_lds[tid + 256] = tanhf(h0_in[b * N_HID + tid + 256]);

  // cache own w_hh row slice in registers (read every step, never changes)
  const float* whrow = w_hh + (size_t)jg * N_HID + i0;
  float4 wh[8];
#pragma unroll
  for (int k = 0; k < 8; ++k) wh[k] = *(const float4*)&whrow[k * 4];

  const float bet = beta[jg];
  const float sb  = sqrtf(bet);
  const float al  = alpha[jg];
  const float sqa = sqrtf(al);
  const float bh  = b_hh[jg];
  float h_reg = h0_in[b * N_HID + jg];  // leaders

  float4 d[8];
#pragma unroll
  for (int k = 0; k < 8; ++k) d[k] = make_float4(0.f, 0.f, 0.f, 0.f);

  __syncthreads();

  unsigned target = 0;
  const unsigned nb = (unsigned)(b * N_HID * N_HID) + (unsigned)jg;

  for (int t = 0; t < T_STEPS; ++t) {
    const int q = (t + 1) & 1;
    const unsigned k1x = __builtin_amdgcn_readfirstlane(keyl[t * 4 + 0]);
    const unsigned k1y = __builtin_amdgcn_readfirstlane(keyl[t * 4 + 1]);
    const unsigned k2x = __builtin_amdgcn_readfirstlane(keyl[t * 4 + 2]);
    const unsigned k2y = __builtin_amdgcn_readfirstlane(keyl[t * 4 + 3]);
    const float ajg = a_lds[jg];

    // ---- accumulate a.diff and a.w_hh^T (bit-identical order to r2) ----
    float accd = 0.f, accw = 0.f;
#pragma unroll
    for (int k = 0; k < 8; ++k) {
      float4 av = *(const float4*)&a_lds[i0 + k * 4];
      float4 wv = wh[k];
      accw = fmaf(av.x, wv.x, accw); accw = fmaf(av.y, wv.y, accw);
      accw = fmaf(av.z, wv.z, accw); accw = fmaf(av.w, wv.w, accw);
      accd = fmaf(av.x, d[k].x, accd); accd = fmaf(av.y, d[k].y, accd);
      accd = fmaf(av.z, d[k].z, accd); accd = fmaf(av.w, d[k].w, accd);
    }
#pragma unroll
    for (int m = 1; m < 16; m <<= 1) {
      accd += __shfl_xor(accd, m);
      accw += __shfl_xor(accw, m);
    }

    // ---- leaders: h update + publish (early, so data is in flight) ----
    if (leader) {
      const float xw = xw_lds[t * JPW + jl];
      float tmp = ((xw + accw) + bh) + accd;
      float hn = (1.f - al) * h_reg + al * tmp;
      if (t >= NOISE_START_T) {
        unsigned m0 = (unsigned)(b * N_HID + jg);
        hn += (nrm_from_bits(rbits(k1x, k1y, m0)) * 0.05f) * sqa;
      }
      h_reg = hn;
      float an = tanhf(hn);
      pubf(hex  + (size_t)(q * B_SZ + b) * N_HID + jg, hn);
      pubf(aexb + (size_t)(q * B_SZ + b) * N_HID + jg, an);
      hl[((size_t)b * T_STEPS + t) * N_HID + jg] = hn;
      if (t == T_STEPS - 1) hid[b * N_HID + jg] = hn;
    }

    // ---- noise gen + diff update (hides barrier skew; r2-exact arithmetic) ----
#pragma unroll
    for (int k = 0; k < 8; ++k) {
      float4 av = *(const float4*)&a_lds[i0 + k * 4];
      const unsigned n = nb + (unsigned)(i0 + k * 4) * 512u;
      float z0 = nrm_from_bits(rbits(k2x, k2y, n));
      float z1 = nrm_from_bits(rbits(k2x, k2y, n + 512u));
      float z2 = nrm_from_bits(rbits(k2x, k2y, n + 1024u));
      float z3 = nrm_from_bits(rbits(k2x, k2y, n + 1536u));
      d[k].x = d[k].x + bet * ((z0 * 0.002f) * sb - av.x * ajg);
      d[k].y = d[k].y + bet * ((z1 * 0.002f) * sb - av.y * ajg);
      d[k].z = d[k].z + bet * ((z2 * 0.002f) * sb - av.z * ajg);
      d[k].w = d[k].w + bet * ((z3 * 0.002f) * sb - av.w * ajg);
    }

    // ---- per-batch barrier: relaxed-only (no L2 wb/inv) ----
    __syncthreads();  // drains vmcnt of ALL waves -> publishes at coherence point
    target += WPB;
    if (tid == 0) {
      __hip_atomic_fetch_add(cnt, 1u, __ATOMIC_RELAXED, __HIP_MEMORY_SCOPE_AGENT);
      while (__hip_atomic_load(cnt, __ATOMIC_RELAXED, __HIP_MEMORY_SCOPE_AGENT) < target)
        __builtin_amdgcn_s_sleep(1);
    }
    __builtin_amdgcn_sched_barrier(0);
    __syncthreads();

    // ---- refill a (and h for blk0) from published slots ----
    {
      float* aq = aexb + (size_t)(q * B_SZ + b) * N_HID;
      float a0v = rdf(aq + tid);
      float a1v = rdf(aq + tid + 256);
      a_lds[tid] = a0v; a_lds[tid + 256] = a1v;
      if (blk == 0) {
        float* hq = hex + (size_t)(q * B_SZ + b) * N_HID;
        h_lds[tid] = rdf(hq + tid);
        h_lds[tid + 256] = rdf(hq + tid + 256);
      }
    }
    __syncthreads();

    if (blk == 0) {  // out-projection, bit-identical reduce to r2
      const int o = tid & 15, qq = tid >> 4;
      const float* wo = w_out + o * N_HID;
      float p = 0.f;
#pragma unroll
      for (int m = 0; m < 32; ++m) { int j = qq * 32 + m; p = fmaf(h_lds[j], wo[j], p); }
      olred[tid] = p;
      __syncthreads();
      if (tid < N_OUT) {
        float s = 0.f;
#pragma unroll
        for (int m = 0; m < 16; ++m) s += olred[m * 16 + tid];
        ol[((size_t)b * T_STEPS + t) * N_OUT + tid] = s;
      }
    }
  }

  // ---- epilogue: registers -> LDS (union'd) -> transposed write of new_j ----
  __syncthreads();
#pragma unroll
  for (int k = 0; k < 8; ++k) *(float4*)&buf[jl * N_HID + i0 + k * 4] = d[k];
  __syncthreads();
#pragma unroll
  for (int c = 0; c < 2; ++c) {
    const int i = c * 256 + tid;
    const float* whr = w_hh + (size_t)i * N_HID + blk * JPW;
    float* orow = nj + (size_t)i * N_HID + blk * JPW;
#pragma unroll
    for (int jj = 0; jj < JPW; ++jj) orow[jj] = buf[jj * N_HID + i] + whr[jj];
  }
}

extern "C" void kernel_launch(void* const* d_in, const int* in_sizes, int n_in,
                              void* d_out, int out_size, void* d_ws, size_t ws_size,
                              hipStream_t stream) {
  const float* x     = (const float*)d_in[0];
  const float* h0    = (const float*)d_in[1];
  const float* win   = (const float*)d_in[2];
  const float* whh   = (const float*)d_in[3];
  const float* bhh   = (const float*)d_in[4];
  const float* wout  = (const float*)d_in[5];
  const float* alpha = (const float*)d_in[6];
  const float* beta  = (const float*)d_in[7];
  (void)in_sizes; (void)n_in; (void)out_size; (void)ws_size;

  hipMemsetAsync(d_ws, 0, CNT_BYTES, stream);  // zero per-batch barrier counters
  unsigned* cnts = (unsigned*)d_ws;
  float* wsf = (float*)((char*)d_ws + CNT_BYTES);  // hex[2][B][512] + aex[2][B][512]
  rnn_fused<<<NWG, WGS, 0, stream>>>(x, h0, win, whh, bhh, wout, alpha, beta,
                                     (float*)d_out, wsf, cnts);
}

// Round 4
// 2083.369 us; speedup vs baseline: 2.0908x; 1.0925x over previous
//
#include <hip/hip_runtime.h>

#define B_SZ 32
#define T_STEPS 64
#define N_IN 64
#define N_HID 512
#define N_OUT 16
#define NOISE_START_T 16

#define WGS 256
#define WPB 32            // workgroups per batch
#define JPW 16            // j columns per WG
#define NWG (B_SZ * WPB)  // 1024

// d_out float offsets (hidden_list, output_list, hidden, new_j)
#define HL_OFF  0
#define OL_OFF  (B_SZ * T_STEPS * N_HID)
#define HID_OFF (OL_OFF + B_SZ * T_STEPS * N_OUT)
#define NJ_OFF  (HID_OFF + B_SZ * N_HID)

#define CNT_BYTES 4096

__device__ __forceinline__ void tf2x32(unsigned k0, unsigned k1, unsigned x0, unsigned x1,
                                       unsigned& o0, unsigned& o1) {
  unsigned ks2 = k0 ^ k1 ^ 0x1BD11BDAu;
#define TFR(r) { x0 += x1; x1 = (x1 << (r)) | (x1 >> (32 - (r))); x1 ^= x0; }
  x0 += k0; x1 += k1;
  TFR(13) TFR(15) TFR(26) TFR(6)
  x0 += k1; x1 += ks2 + 1u;
  TFR(17) TFR(29) TFR(16) TFR(24)
  x0 += ks2; x1 += k0 + 2u;
  TFR(13) TFR(15) TFR(26) TFR(6)
  x0 += k0; x1 += k1 + 3u;
  TFR(17) TFR(29) TFR(16) TFR(24)
  x0 += k1; x1 += ks2 + 4u;
  TFR(13) TFR(15) TFR(26) TFR(6)
  x0 += ks2; x1 += k0 + 5u;
#undef TFR
  o0 = x0; o1 = x1;
}

// JAX threefry_partitionable: out[n] = o0^o1 of tf(key, (0, n))  [verified r1]
__device__ __forceinline__ unsigned rbits(unsigned kx, unsigned ky, unsigned n) {
  unsigned a, b; tf2x32(kx, ky, 0u, n, a, b); return a ^ b;
}

// XLA-exact uniform->normal with factored fast-log (validated r2/r3, absmax 4.0)
__device__ __forceinline__ float nrm_from_bits(unsigned bits) {
  const float lo = -0.99999994039535522461f;
  float f = __uint_as_float((bits >> 9) | 0x3F800000u) - 1.0f;
  float u = fmaxf(lo, f * 2.0f + lo);
  float w = -__logf((1.0f - u) * (1.0f + u));
  float p;
  if (w < 5.0f) {
    w -= 2.5f;
    p =            2.81022636e-08f;
    p = fmaf(p, w, 3.43273939e-07f);
    p = fmaf(p, w, -3.5233877e-06f);
    p = fmaf(p, w, -4.39150654e-06f);
    p = fmaf(p, w, 0.00021858087f);
    p = fmaf(p, w, -0.00125372503f);
    p = fmaf(p, w, -0.00417768164f);
    p = fmaf(p, w, 0.246640727f);
    p = fmaf(p, w, 1.50140941f);
  } else {
    w = sqrtf(w) - 3.0f;
    p =            -0.000200214257f;
    p = fmaf(p, w, 0.000100950558f);
    p = fmaf(p, w, 0.00134934322f);
    p = fmaf(p, w, -0.00367342844f);
    p = fmaf(p, w, 0.00573950773f);
    p = fmaf(p, w, -0.0076224613f);
    p = fmaf(p, w, 0.00943887047f);
    p = fmaf(p, w, 1.00167406f);
    p = fmaf(p, w, 2.83297682f);
  }
  return 1.41421356f * (p * u);
}

// relaxed agent-scope atomics: MALL-coherent, NO L2 writeback/invalidate
__device__ __forceinline__ void pubf(float* p, float v) {
  __hip_atomic_store(p, v, __ATOMIC_RELAXED, __HIP_MEMORY_SCOPE_AGENT);
}
__device__ __forceinline__ float rdf(float* p) {
  return __hip_atomic_load(p, __ATOMIC_RELAXED, __HIP_MEMORY_SCOPE_AGENT);
}

__global__ __launch_bounds__(WGS, 4) __attribute__((amdgpu_waves_per_eu(4, 4)))
void rnn_fused(
    const float* __restrict__ x, const float* __restrict__ h0_in,
    const float* __restrict__ w_in, const float* __restrict__ w_hh,
    const float* __restrict__ b_hh, const float* __restrict__ w_out,
    const float* __restrict__ alpha, const float* __restrict__ beta,
    float* __restrict__ out, float* __restrict__ wsf, unsigned* __restrict__ cnts) {
  // LDS = exactly 40960 B -> 4 WGs/CU (160 KB/CU), which (a) makes all 1024 WGs
  // co-resident (barrier safety) and (b) caps occupancy at 4 waves/SIMD so the
  // register allocator gets the full 128-VGPR budget -> no scratch spills.
  __shared__ __align__(16) unsigned char smem[40960];
  float* wh_lds   = (float*)smem;                // [16][512] w_hh rows; reused as epilogue buf
  float* a_lds    = (float*)(smem + 32768);      // [512]
  float* xw_lds   = (float*)(smem + 34816);      // [64][16]
  unsigned* keyl  = (unsigned*)(smem + 38912);   // [64][4]
  float* olred    = (float*)(smem + 39936);      // [256]

  const int tid = threadIdx.x;
  const int b   = blockIdx.x >> 5;
  const int blk = blockIdx.x & 31;
  const int jl  = tid >> 4;            // owned column (local)
  const int ib  = tid & 15;            // i sub-block
  const int jg  = blk * JPW + jl;      // owned global column
  const bool leader = (ib == 0);

  float* hl  = out + HL_OFF;
  float* ol  = out + OL_OFF;
  float* hid = out + HID_OFF;
  float* nj  = out + NJ_OFF + (size_t)b * (N_HID * N_HID);
  unsigned* cnt = cnts + (size_t)b * 32;
  float* hex  = wsf;                      // [2][B][512] published h
  float* aexb = wsf + 2 * B_SZ * N_HID;   // [2][B][512] published a=tanh(h)

  // ---- prologue ----
  if (tid < T_STEPS) {
    unsigned f0, f1, a0, a1, b0, b1;
    tf2x32(0u, 1234u, 0u, (unsigned)tid, f0, f1);
    tf2x32(f0, f1, 0u, 0u, a0, a1);   // k1 (neuron noise)
    tf2x32(f0, f1, 0u, 1u, b0, b1);   // k2 (synaptic noise)
    keyl[tid * 4 + 0] = a0; keyl[tid * 4 + 1] = a1;
    keyl[tid * 4 + 2] = b0; keyl[tid * 4 + 3] = b1;
  }
  // stage w_hh rows [blk*16, blk*16+16) into LDS (coalesced, once)
#pragma unroll 4
  for (int idx = tid; idx < JPW * N_HID; idx += WGS)
    wh_lds[idx] = w_hh[(size_t)(blk * JPW) * N_HID + idx];
  // xw_lds[t][jj] = x[b,t,:] . w_in[blk*16+jj,:]
#pragma unroll
  for (int r = 0; r < 4; ++r) {
    int m = r * 256 + tid;
    int tt = m >> 4, jj = m & 15;
    const float* xr = x + ((size_t)b * T_STEPS + tt) * N_IN;
    const float* wr = w_in + (size_t)(blk * JPW + jj) * N_IN;
    float s = 0.f;
#pragma unroll
    for (int k = 0; k < N_IN; ++k) s = fmaf(xr[k], wr[k], s);
    xw_lds[tt * JPW + jj] = s;
  }
  a_lds[tid]       = tanhf(h0_in[b * N_HID + tid]);
  a_lds[tid + 256] = tanhf(h0_in[b * N_HID + tid + 256]);

  const float bet = beta[jg];
  const float sb  = sqrtf(bet);
  const float al  = alpha[jg];
  const float sqa = sqrtf(al);
  const float bh  = b_hh[jg];
  float h_reg = h0_in[b * N_HID + jg];  // used by leaders

  // plastic deviation: thread owns rows i = k*64 + ib*4 + e of column jg
  float4 d[8];
#pragma unroll
  for (int k = 0; k < 8; ++k) d[k] = make_float4(0.f, 0.f, 0.f, 0.f);

  __syncthreads();

  unsigned target = 0;
  const unsigned nb = (unsigned)(b * N_HID * N_HID) + (unsigned)jg;

  for (int t = 0; t < T_STEPS; ++t) {
    const int q = (t + 1) & 1;
    const unsigned k1x = __builtin_amdgcn_readfirstlane(keyl[t * 4 + 0]);
    const unsigned k1y = __builtin_amdgcn_readfirstlane(keyl[t * 4 + 1]);
    const unsigned k2x = __builtin_amdgcn_readfirstlane(keyl[t * 4 + 2]);
    const unsigned k2y = __builtin_amdgcn_readfirstlane(keyl[t * 4 + 3]);
    const float ajg = a_lds[jg];

    // ---- accumulate a.diff and a.w_hh^T over owned rows ----
    float accd = 0.f, accw = 0.f;
#pragma unroll
    for (int k = 0; k < 8; ++k) {
      const int i = k * 64 + ib * 4;   // contiguous 16B per lane -> conflict-free
      float4 av = *(const float4*)&a_lds[i];
      float4 wv = *(const float4*)&wh_lds[jl * N_HID + i];
      accw = fmaf(av.x, wv.x, accw); accw = fmaf(av.y, wv.y, accw);
      accw = fmaf(av.z, wv.z, accw); accw = fmaf(av.w, wv.w, accw);
      accd = fmaf(av.x, d[k].x, accd); accd = fmaf(av.y, d[k].y, accd);
      accd = fmaf(av.z, d[k].z, accd); accd = fmaf(av.w, d[k].w, accd);
    }
#pragma unroll
    for (int m = 1; m < 16; m <<= 1) {
      accd += __shfl_xor(accd, m);
      accw += __shfl_xor(accw, m);
    }

    // ---- leaders: h update + publish early (in flight before barrier) ----
    if (leader) {
      const float xw = xw_lds[t * JPW + jl];
      float tmp = ((xw + accw) + bh) + accd;
      float hn = (1.f - al) * h_reg + al * tmp;
      if (t >= NOISE_START_T) {
        unsigned m0 = (unsigned)(b * N_HID + jg);
        hn += (nrm_from_bits(rbits(k1x, k1y, m0)) * 0.05f) * sqa;
      }
      h_reg = hn;
      float an = tanhf(hn);
      pubf(hex  + (size_t)(q * B_SZ + b) * N_HID + jg, hn);
      pubf(aexb + (size_t)(q * B_SZ + b) * N_HID + jg, an);
      hl[((size_t)b * T_STEPS + t) * N_HID + jg] = hn;
      if (t == T_STEPS - 1) hid[b * N_HID + jg] = hn;
    }

    // ---- synaptic noise + diff update (hides barrier skew) ----
#pragma unroll
    for (int k = 0; k < 8; ++k) {
      const int i = k * 64 + ib * 4;
      float4 av = *(const float4*)&a_lds[i];
      const unsigned n = nb + (unsigned)i * 512u;
      float z0 = nrm_from_bits(rbits(k2x, k2y, n));
      float z1 = nrm_from_bits(rbits(k2x, k2y, n + 512u));
      float z2 = nrm_from_bits(rbits(k2x, k2y, n + 1024u));
      float z3 = nrm_from_bits(rbits(k2x, k2y, n + 1536u));
      d[k].x = d[k].x + bet * ((z0 * 0.002f) * sb - av.x * ajg);
      d[k].y = d[k].y + bet * ((z1 * 0.002f) * sb - av.y * ajg);
      d[k].z = d[k].z + bet * ((z2 * 0.002f) * sb - av.z * ajg);
      d[k].w = d[k].w + bet * ((z3 * 0.002f) * sb - av.w * ajg);
    }

    // ---- per-batch barrier: relaxed-only atomics (no cache maintenance) ----
    __syncthreads();  // all waves drain vmcnt -> publishes visible at MALL
    target += WPB;
    if (tid == 0) {
      __hip_atomic_fetch_add(cnt, 1u, __ATOMIC_RELAXED, __HIP_MEMORY_SCOPE_AGENT);
      while (__hip_atomic_load(cnt, __ATOMIC_RELAXED, __HIP_MEMORY_SCOPE_AGENT) < target)
        __builtin_amdgcn_s_sleep(1);
    }
    __builtin_amdgcn_sched_barrier(0);
    __syncthreads();

    // ---- refill a from published slots ----
    {
      float* aq = aexb + (size_t)(q * B_SZ + b) * N_HID;
      a_lds[tid]       = rdf(aq + tid);
      a_lds[tid + 256] = rdf(aq + tid + 256);
    }
    __syncthreads();

    if (blk == 0) {  // out-projection: read h via relaxed atomics from hex
      float* hq = hex + (size_t)(q * B_SZ + b) * N_HID;
      const int o = tid & 15, qq = tid >> 4;
      const float* wo = w_out + o * N_HID;
      float p = 0.f;
#pragma unroll
      for (int m = 0; m < 32; ++m) { int j = qq * 32 + m; p = fmaf(rdf(hq + j), wo[j], p); }
      olred[tid] = p;
      __syncthreads();
      if (tid < N_OUT) {
        float s = 0.f;
#pragma unroll
        for (int m = 0; m < 16; ++m) s += olred[m * 16 + tid];
        ol[((size_t)b * T_STEPS + t) * N_OUT + tid] = s;
      }
    }
  }

  // ---- epilogue: d regs -> LDS (reusing wh_lds) -> transposed new_j write ----
  __syncthreads();
#pragma unroll
  for (int k = 0; k < 8; ++k)
    *(float4*)&wh_lds[jl * N_HID + k * 64 + ib * 4] = d[k];
  __syncthreads();
#pragma unroll
  for (int c = 0; c < 2; ++c) {
    const int i = c * 256 + tid;
    const float* whr = w_hh + (size_t)i * N_HID + blk * JPW;
    float* orow = nj + (size_t)i * N_HID + blk * JPW;
#pragma unroll
    for (int jj = 0; jj < JPW; ++jj) orow[jj] = wh_lds[jj * N_HID + i] + whr[jj];
  }
}

extern "C" void kernel_launch(void* const* d_in, const int* in_sizes, int n_in,
                              void* d_out, int out_size, void* d_ws, size_t ws_size,
                              hipStream_t stream) {
  const float* x     = (const float*)d_in[0];
  const float* h0    = (const float*)d_in[1];
  const float* win   = (const float*)d_in[2];
  const float* whh   = (const float*)d_in[3];
  const float* bhh   = (const float*)d_in[4];
  const float* wout  = (const float*)d_in[5];
  const float* alpha = (const float*)d_in[6];
  const float* beta  = (const float*)d_in[7];
  (void)in_sizes; (void)n_in; (void)out_size; (void)ws_size;

  hipMemsetAsync(d_ws, 0, CNT_BYTES, stream);  // zero per-batch barrier counters
  unsigned* cnts = (unsigned*)d_ws;
  float* wsf = (float*)((char*)d_ws + CNT_BYTES);  // hex[2][B][512] + aex[2][B][512]
  rnn_fused<<<NWG, WGS, 0, stream>>>(x, h0, win, whh, bhh, wout, alpha, beta,
                                     (float*)d_out, wsf, cnts);
}